// Round 6
// baseline (267.895 us; speedup 1.0000x reference)
//
#include <hip/hip_runtime.h>
#include <hip/hip_bf16.h>
#include <stdint.h>

// RelMHAtt: B=4 S=512 HIDDEN=1024 H=16 D=64 R=64
// Split pipeline: convert(fp32->bf16) -> proj GEMM x3 -> rel v5 (all-register
// streaming, zero LDS) -> attention (register scores) -> out GEMM fp32.
// rel v5: thread=(row r, h-quad hq, chunk cg); Wr slice in 64 VGPRs loaded
// once; 4 coalesced float4 loads/row; quad shfl-reduce; 1 bf16 store.

typedef __attribute__((ext_vector_type(8))) short bf16x8;
typedef __attribute__((ext_vector_type(4))) float f32x4;

__device__ inline unsigned short f2bf(float f) {
    __hip_bfloat16 h = __float2bfloat16(f);
    return *reinterpret_cast<unsigned short*>(&h);
}
__device__ inline float bf2f(unsigned short u) {
    unsigned int t = ((unsigned int)u) << 16;
    return __builtin_bit_cast(float, t);
}

// ---------------------------------------------------------------- convert
// dst layout (bf16): xq[2M] xk[2M] xv[2M] Wq[1M] Wk[1M] Wv[1M] Wm[1M]
__global__ __launch_bounds__(256) void convert_kernel(
    const float* __restrict__ q, const float* __restrict__ k, const float* __restrict__ v,
    const float* __restrict__ wq, const float* __restrict__ wk, const float* __restrict__ wv,
    const float* __restrict__ wm, unsigned short* __restrict__ dst)
{
    const long long X = 2097152LL, Wn = 1048576LL;
    long long e = 4LL * ((long long)blockIdx.x * 256 + threadIdx.x);
    const float* s;
    long long o = e;
    if      (o < X)          { s = q; }
    else if (o < 2*X)        { s = k;  o -= X; }
    else if (o < 3*X)        { s = v;  o -= 2*X; }
    else if (o < 3*X + Wn)   { s = wq; o -= 3*X; }
    else if (o < 3*X + 2*Wn) { s = wk; o -= 3*X + Wn; }
    else if (o < 3*X + 3*Wn) { s = wv; o -= 3*X + 2*Wn; }
    else                     { s = wm; o -= 3*X + 3*Wn; }
    float4 val = *reinterpret_cast<const float4*>(s + o);
    ushort4 u;
    u.x = f2bf(val.x); u.y = f2bf(val.y); u.z = f2bf(val.z); u.w = f2bf(val.w);
    *reinterpret_cast<ushort4*>(dst + e) = u;
}

// ---------------------------------------------------------------- GEMM
// C[m,n] = sum_k A[m,k]*B[n,k] + bias[n];  BM=64, BN=128, BK=32; 4 waves.
// mode 0: f32 [M,1024]; 1: bf16 [M,1024]; 2: bf16*0.125; 3: bf16 vht[b][h][d][s]
struct GemmJob { const unsigned short* A; const unsigned short* B; const float* bias; char* C; int mode; };
struct Gemm3 { GemmJob j[3]; };

__global__ __launch_bounds__(256) void gemm_bt(Gemm3 g)
{
    GemmJob jb = g.j[blockIdx.z];
    const unsigned short* __restrict__ A = jb.A;
    const unsigned short* __restrict__ B = jb.B;
    __shared__ alignas(16) unsigned short As[2][2048];
    __shared__ alignas(16) unsigned short Bs[2][4096];
    int tid = threadIdx.x;
    int bm0 = blockIdx.x * 64, bn0 = blockIdx.y * 128;
    int wid = tid >> 6, lane = tid & 63;
    int fr = lane & 15, fq = lane >> 4;
    int wm = (wid >> 1) * 32, wn = (wid & 1) * 64;

    f32x4 acc[2][4];
    f32x4 z4 = {0.f, 0.f, 0.f, 0.f};
    for (int i = 0; i < 2; i++) for (int j = 0; j < 4; j++) acc[i][j] = z4;

    auto stage = [&](int buf, int kt) {
        {
            int ci = tid;
            int row = ci >> 2, kc = ci & 3;
            const unsigned short* ga = A + (long long)(bm0 + row) * 1024 + kt * 32 + kc * 8;
            __builtin_amdgcn_global_load_lds((const __attribute__((address_space(1))) void*)ga,
                (__attribute__((address_space(3))) void*)(&As[buf][ci * 8]), 16, 0, 0);
        }
        #pragma unroll
        for (int i = 0; i < 2; i++) {
            int ci = tid + 256 * i;
            int row = ci >> 2, kc = ci & 3;
            const unsigned short* gb = B + (long long)(bn0 + row) * 1024 + kt * 32 + kc * 8;
            __builtin_amdgcn_global_load_lds((const __attribute__((address_space(1))) void*)gb,
                (__attribute__((address_space(3))) void*)(&Bs[buf][ci * 8]), 16, 0, 0);
        }
    };
    auto compute = [&](int buf) {
        bf16x8 a[2], b[4];
        #pragma unroll
        for (int fm = 0; fm < 2; fm++)
            a[fm] = *reinterpret_cast<const bf16x8*>(&As[buf][(wm + fm*16 + fr)*32 + fq*8]);
        #pragma unroll
        for (int fn = 0; fn < 4; fn++)
            b[fn] = *reinterpret_cast<const bf16x8*>(&Bs[buf][(wn + fn*16 + fr)*32 + fq*8]);
        #pragma unroll
        for (int fm = 0; fm < 2; fm++)
            #pragma unroll
            for (int fn = 0; fn < 4; fn++)
                acc[fm][fn] = __builtin_amdgcn_mfma_f32_16x16x32_bf16(a[fm], b[fn], acc[fm][fn], 0, 0, 0);
    };

    stage(0, 0);
    asm volatile("s_waitcnt vmcnt(0)" ::: "memory");
    __syncthreads();
    int cur = 0;
    for (int kt = 0; kt < 31; kt++) {
        stage(cur ^ 1, kt + 1);
        compute(cur);
        asm volatile("s_waitcnt vmcnt(0)" ::: "memory");
        __syncthreads();
        cur ^= 1;
    }
    compute(cur);

    int mode = jb.mode;
    #pragma unroll
    for (int fm = 0; fm < 2; fm++) {
        #pragma unroll
        for (int fn = 0; fn < 4; fn++) {
            int col = bn0 + wn + fn*16 + fr;
            float bv = jb.bias[col];
            f32x4 vacc = acc[fm][fn];
            #pragma unroll
            for (int r = 0; r < 4; r++) {
                int m = bm0 + wm + fm*16 + fq*4 + r;
                float val = vacc[r] + bv;
                if (mode == 0) {
                    reinterpret_cast<float*>(jb.C)[(long long)m*1024 + col] = val;
                } else if (mode == 1) {
                    reinterpret_cast<unsigned short*>(jb.C)[(long long)m*1024 + col] = f2bf(val);
                } else if (mode == 2) {
                    reinterpret_cast<unsigned short*>(jb.C)[(long long)m*1024 + col] = f2bf(val * 0.125f);
                } else {
                    int bb = m >> 9, ss = m & 511;
                    int hh = col >> 6, dd = col & 63;
                    reinterpret_cast<unsigned short*>(jb.C)[(((long long)bb*16 + hh)*64 + dd)*512 + ss] = f2bf(val);
                }
            }
        }
    }
}

// ---------------------------------------------------------------- rel bias v5
// biasT[b][h][q][k] = log(max(dot(rel[b,q,k,:], Wr[h,:]) + br[h], 1e-6)) bf16.
// Zero LDS. lane = r*16 + hq*4 + cg. Wr slice (4h x 16 floats) in registers.
// 4 passes of 16 rows per block (64 rows/block).
__global__ __launch_bounds__(256) void rel_kernel(
    const float* __restrict__ rel, const float* __restrict__ Wr, const float* __restrict__ br,
    unsigned short* __restrict__ biasT)
{
    int tid = threadIdx.x;
    int wid = tid >> 6, lane = tid & 63;
    int r  = lane >> 4;
    int hq = (lane >> 2) & 3;
    int cg = lane & 3;

    // Wr slice in registers: h = hq*4..hq*4+3, floats [cg*16, cg*16+16)
    float4 wreg[4][4];
    #pragma unroll
    for (int hh = 0; hh < 4; hh++)
        #pragma unroll
        for (int j = 0; j < 4; j++)
            wreg[hh][j] = *reinterpret_cast<const float4*>(Wr + (hq*4 + hh)*64 + cg*16 + j*4);
    float brv[4];
    #pragma unroll
    for (int hh = 0; hh < 4; hh++) brv[hh] = br[hq*4 + hh];

    long long row0 = (long long)blockIdx.x * 64 + wid*4 + r;
    #pragma unroll
    for (int pass = 0; pass < 4; pass++) {
        long long row = row0 + pass*16;
        const float* rp = rel + row*64 + cg*16;
        float4 rc[4];
        #pragma unroll
        for (int j = 0; j < 4; j++) rc[j] = *reinterpret_cast<const float4*>(rp + j*4);
        float acc[4] = {0.f, 0.f, 0.f, 0.f};
        #pragma unroll
        for (int hh = 0; hh < 4; hh++)
            #pragma unroll
            for (int j = 0; j < 4; j++)
                acc[hh] += rc[j].x*wreg[hh][j].x + rc[j].y*wreg[hh][j].y
                         + rc[j].z*wreg[hh][j].z + rc[j].w*wreg[hh][j].w;
        // reduce across cg lanes (lane bits 0-1)
        #pragma unroll
        for (int hh = 0; hh < 4; hh++) {
            acc[hh] += __shfl_xor(acc[hh], 1, 64);
            acc[hh] += __shfl_xor(acc[hh], 2, 64);
        }
        int b = (int)(row >> 18), q = (int)((row >> 9) & 511), k = (int)(row & 511);
        #pragma unroll
        for (int j = 0; j < 4; j++) {
            if (j == cg) {   // static acc index; lane cg stores h = hq*4 + cg
                int h = hq*4 + j;
                float val = acc[j] + brv[j];
                biasT[(((long long)(b*16 + h)*512 + q) << 9) + k] =
                    f2bf(__logf(fmaxf(val, 1e-6f)));
            }
        }
    }
}

// ---------------------------------------------------------------- attention
__global__ __launch_bounds__(256) void attn_kernel(
    const unsigned short* __restrict__ qh, const unsigned short* __restrict__ kh,
    const unsigned short* __restrict__ vht, const unsigned short* __restrict__ biasT,
    const unsigned char* __restrict__ mask, unsigned short* __restrict__ atted)
{
    __shared__ alignas(16) unsigned short Pl[16][520];
    __shared__ float pmax[4][16];
    __shared__ float psum[4][16];
    int tid = threadIdx.x;
    int wid = tid >> 6, lane = tid & 63;
    int fr = lane & 15, fq = lane >> 4;
    int q0 = blockIdx.x * 16;
    int h = blockIdx.y, b = blockIdx.z;

    bf16x8 aq[2];
    #pragma unroll
    for (int df = 0; df < 2; df++)
        aq[df] = *reinterpret_cast<const bf16x8*>(
            qh + (long long)(b*512 + q0 + fr)*1024 + h*64 + df*32 + fq*8);

    f32x4 s[8];
    #pragma unroll
    for (int kt = 0; kt < 8; kt++) {
        int cb = wid*128 + kt*16;
        f32x4 a4 = {0.f,0.f,0.f,0.f};
        #pragma unroll
        for (int df = 0; df < 2; df++) {
            bf16x8 bk = *reinterpret_cast<const bf16x8*>(
                kh + (long long)(b*512 + cb + fr)*1024 + h*64 + df*32 + fq*8);
            a4 = __builtin_amdgcn_mfma_f32_16x16x32_bf16(aq[df], bk, a4, 0, 0, 0);
        }
        s[kt] = a4;
    }

    const unsigned short* bbase = biasT + ((long long)(b*16 + h)*512 + q0)*512;
    #pragma unroll
    for (int kt = 0; kt < 8; kt++) {
        int col = wid*128 + kt*16 + fr;
        bool mk = mask[b*512 + col] != 0;
        #pragma unroll
        for (int r = 0; r < 4; r++) {
            float bias = bf2f(bbase[(fq*4 + r)*512 + col]);
            float val = s[kt][r] + bias;
            s[kt][r] = mk ? -1e9f : val;
        }
    }

    float rm[4];
    #pragma unroll
    for (int r = 0; r < 4; r++) {
        float m = s[0][r];
        #pragma unroll
        for (int kt = 1; kt < 8; kt++) m = fmaxf(m, s[kt][r]);
        #pragma unroll
        for (int x = 1; x < 16; x <<= 1) m = fmaxf(m, __shfl_xor(m, x, 64));
        rm[r] = m;
    }
    #pragma unroll
    for (int r = 0; r < 4; r++)
        if (fr == r) pmax[wid][fq*4 + r] = rm[r];
    __syncthreads();
    #pragma unroll
    for (int r = 0; r < 4; r++) {
        float m = pmax[0][fq*4 + r];
        m = fmaxf(m, pmax[1][fq*4 + r]);
        m = fmaxf(m, pmax[2][fq*4 + r]);
        m = fmaxf(m, pmax[3][fq*4 + r]);
        rm[r] = m;
    }

    float sum[4] = {0.f, 0.f, 0.f, 0.f};
    #pragma unroll
    for (int kt = 0; kt < 8; kt++) {
        int col = wid*128 + kt*16 + fr;
        #pragma unroll
        for (int r = 0; r < 4; r++) {
            float p = __expf(s[kt][r] - rm[r]);
            sum[r] += p;
            Pl[fq*4 + r][col] = f2bf(p);
        }
    }
    #pragma unroll
    for (int r = 0; r < 4; r++) {
        float sv = sum[r];
        #pragma unroll
        for (int x = 1; x < 16; x <<= 1) sv += __shfl_xor(sv, x, 64);
        sum[r] = sv;
    }
    #pragma unroll
    for (int r = 0; r < 4; r++)
        if (fr == r) psum[wid][fq*4 + r] = sum[r];
    __syncthreads();
    float sumr[4];
    #pragma unroll
    for (int r = 0; r < 4; r++)
        sumr[r] = psum[0][fq*4+r] + psum[1][fq*4+r] + psum[2][fq*4+r] + psum[3][fq*4+r];

    int d0 = wid * 16;
    f32x4 acco = {0.f,0.f,0.f,0.f};
    for (int c = 0; c < 16; c++) {
        bf16x8 pa = *reinterpret_cast<const bf16x8*>(&Pl[fr][c*32 + fq*8]);
        bf16x8 bv = *reinterpret_cast<const bf16x8*>(
            vht + ((long long)(b*16 + h)*64 + d0 + fr)*512 + c*32 + fq*8);
        acco = __builtin_amdgcn_mfma_f32_16x16x32_bf16(pa, bv, acco, 0, 0, 0);
    }
    #pragma unroll
    for (int r = 0; r < 4; r++) {
        float val = acco[r] / sumr[r];
        atted[(long long)(b*512 + q0 + fq*4 + r)*1024 + h*64 + d0 + fr] = f2bf(val);
    }
}

// ---------------------------------------------------------------- launch
extern "C" void kernel_launch(void* const* d_in, const int* in_sizes, int n_in,
                              void* d_out, int out_size, void* d_ws, size_t ws_size,
                              hipStream_t stream)
{
    const float* v    = (const float*)d_in[0];
    const float* k    = (const float*)d_in[1];
    const float* q    = (const float*)d_in[2];
    const unsigned char* mask = (const unsigned char*)d_in[3];
    const float* rel  = (const float*)d_in[4];
    const float* Wv   = (const float*)d_in[5];
    const float* bv   = (const float*)d_in[6];
    const float* Wk   = (const float*)d_in[7];
    const float* bk   = (const float*)d_in[8];
    const float* Wq   = (const float*)d_in[9];
    const float* bq   = (const float*)d_in[10];
    const float* Wr   = (const float*)d_in[11];
    const float* br   = (const float*)d_in[12];
    const float* Wm   = (const float*)d_in[13];
    const float* bm   = (const float*)d_in[14];

    const long long MB = 1 << 20;
    char* W = (char*)d_ws;
    unsigned short* xq    = (unsigned short*)(W + 0*MB);
    unsigned short* xk    = (unsigned short*)(W + 4*MB);
    unsigned short* xv    = (unsigned short*)(W + 8*MB);
    unsigned short* Wqb   = (unsigned short*)(W + 12*MB);
    unsigned short* Wkb   = (unsigned short*)(W + 14*MB);
    unsigned short* Wvb   = (unsigned short*)(W + 16*MB);
    unsigned short* Wmb   = (unsigned short*)(W + 18*MB);
    unsigned short* qhb   = (unsigned short*)(W + 20*MB);
    unsigned short* khb   = (unsigned short*)(W + 24*MB);
    unsigned short* vht   = (unsigned short*)(W + 28*MB);
    unsigned short* atted = (unsigned short*)(W + 32*MB);
    unsigned short* biasT = (unsigned short*)(W + 36*MB);  // 32 MB

    convert_kernel<<<10240, 256, 0, stream>>>(q, k, v, Wq, Wk, Wv, Wm, (unsigned short*)W);

    Gemm3 gp;
    gp.j[0] = { xq, Wqb, bq, (char*)qhb, 2 };
    gp.j[1] = { xk, Wkb, bk, (char*)khb, 1 };
    gp.j[2] = { xv, Wvb, bv, (char*)vht, 3 };
    gemm_bt<<<dim3(32, 8, 3), 256, 0, stream>>>(gp);

    rel_kernel<<<16384, 256, 0, stream>>>(rel, Wr, br, biasT);

    attn_kernel<<<dim3(32, 16, 4), 256, 0, stream>>>(qhb, khb, vht, biasT, mask, atted);

    Gemm3 gf;
    gf.j[0] = { atted, Wmb, bm, (char*)d_out, 0 };
    gf.j[1] = gf.j[0];
    gf.j[2] = gf.j[0];
    gemm_bt<<<dim3(32, 8, 1), 256, 0, stream>>>(gf);
}

// Round 7
// 167.966 us; speedup vs baseline: 1.5949x; 1.5949x over previous
//
#include <hip/hip_runtime.h>
#include <hip/hip_bf16.h>
#include <stdint.h>

// RelMHAtt: B=4 S=512 HIDDEN=1024 H=16 D=64 R=64
// Pipeline: convert(fp32->bf16) -> proj GEMM x3 -> rel v6 (MFMA, split-
// precision bf16, zero LDS) -> attention (register scores) -> out GEMM fp32.
// rel v6: [1M,64]x[64,16] via mfma_f32_16x16x32_bf16; A-frags straight from
// global (coalesced), Wr in B-frag registers, C-frag -> packed ushort4 store.

typedef __attribute__((ext_vector_type(8))) short bf16x8;
typedef __attribute__((ext_vector_type(4))) float f32x4;

__device__ inline unsigned short f2bf(float f) {
    __hip_bfloat16 h = __float2bfloat16(f);
    return *reinterpret_cast<unsigned short*>(&h);
}
__device__ inline float bf2f(unsigned short u) {
    unsigned int t = ((unsigned int)u) << 16;
    return __builtin_bit_cast(float, t);
}

// ---------------------------------------------------------------- convert
// dst layout (bf16): xq[2M] xk[2M] xv[2M] Wq[1M] Wk[1M] Wv[1M] Wm[1M]
__global__ __launch_bounds__(256) void convert_kernel(
    const float* __restrict__ q, const float* __restrict__ k, const float* __restrict__ v,
    const float* __restrict__ wq, const float* __restrict__ wk, const float* __restrict__ wv,
    const float* __restrict__ wm, unsigned short* __restrict__ dst)
{
    const long long X = 2097152LL, Wn = 1048576LL;
    long long e = 4LL * ((long long)blockIdx.x * 256 + threadIdx.x);
    const float* s;
    long long o = e;
    if      (o < X)          { s = q; }
    else if (o < 2*X)        { s = k;  o -= X; }
    else if (o < 3*X)        { s = v;  o -= 2*X; }
    else if (o < 3*X + Wn)   { s = wq; o -= 3*X; }
    else if (o < 3*X + 2*Wn) { s = wk; o -= 3*X + Wn; }
    else if (o < 3*X + 3*Wn) { s = wv; o -= 3*X + 2*Wn; }
    else                     { s = wm; o -= 3*X + 3*Wn; }
    float4 val = *reinterpret_cast<const float4*>(s + o);
    ushort4 u;
    u.x = f2bf(val.x); u.y = f2bf(val.y); u.z = f2bf(val.z); u.w = f2bf(val.w);
    *reinterpret_cast<ushort4*>(dst + e) = u;
}

// ---------------------------------------------------------------- GEMM
// C[m,n] = sum_k A[m,k]*B[n,k] + bias[n];  BM=64, BN=128, BK=32; 4 waves.
// mode 0: f32 [M,1024]; 1: bf16 [M,1024]; 2: bf16*0.125; 3: bf16 vht[b][h][d][s]
struct GemmJob { const unsigned short* A; const unsigned short* B; const float* bias; char* C; int mode; };
struct Gemm3 { GemmJob j[3]; };

__global__ __launch_bounds__(256) void gemm_bt(Gemm3 g)
{
    GemmJob jb = g.j[blockIdx.z];
    const unsigned short* __restrict__ A = jb.A;
    const unsigned short* __restrict__ B = jb.B;
    __shared__ alignas(16) unsigned short As[2][2048];
    __shared__ alignas(16) unsigned short Bs[2][4096];
    int tid = threadIdx.x;
    int bm0 = blockIdx.x * 64, bn0 = blockIdx.y * 128;
    int wid = tid >> 6, lane = tid & 63;
    int fr = lane & 15, fq = lane >> 4;
    int wm = (wid >> 1) * 32, wn = (wid & 1) * 64;

    f32x4 acc[2][4];
    f32x4 z4 = {0.f, 0.f, 0.f, 0.f};
    for (int i = 0; i < 2; i++) for (int j = 0; j < 4; j++) acc[i][j] = z4;

    auto stage = [&](int buf, int kt) {
        {
            int ci = tid;
            int row = ci >> 2, kc = ci & 3;
            const unsigned short* ga = A + (long long)(bm0 + row) * 1024 + kt * 32 + kc * 8;
            __builtin_amdgcn_global_load_lds((const __attribute__((address_space(1))) void*)ga,
                (__attribute__((address_space(3))) void*)(&As[buf][ci * 8]), 16, 0, 0);
        }
        #pragma unroll
        for (int i = 0; i < 2; i++) {
            int ci = tid + 256 * i;
            int row = ci >> 2, kc = ci & 3;
            const unsigned short* gb = B + (long long)(bn0 + row) * 1024 + kt * 32 + kc * 8;
            __builtin_amdgcn_global_load_lds((const __attribute__((address_space(1))) void*)gb,
                (__attribute__((address_space(3))) void*)(&Bs[buf][ci * 8]), 16, 0, 0);
        }
    };
    auto compute = [&](int buf) {
        bf16x8 a[2], b[4];
        #pragma unroll
        for (int fm = 0; fm < 2; fm++)
            a[fm] = *reinterpret_cast<const bf16x8*>(&As[buf][(wm + fm*16 + fr)*32 + fq*8]);
        #pragma unroll
        for (int fn = 0; fn < 4; fn++)
            b[fn] = *reinterpret_cast<const bf16x8*>(&Bs[buf][(wn + fn*16 + fr)*32 + fq*8]);
        #pragma unroll
        for (int fm = 0; fm < 2; fm++)
            #pragma unroll
            for (int fn = 0; fn < 4; fn++)
                acc[fm][fn] = __builtin_amdgcn_mfma_f32_16x16x32_bf16(a[fm], b[fn], acc[fm][fn], 0, 0, 0);
    };

    stage(0, 0);
    asm volatile("s_waitcnt vmcnt(0)" ::: "memory");
    __syncthreads();
    int cur = 0;
    for (int kt = 0; kt < 31; kt++) {
        stage(cur ^ 1, kt + 1);
        compute(cur);
        asm volatile("s_waitcnt vmcnt(0)" ::: "memory");
        __syncthreads();
        cur ^= 1;
    }
    compute(cur);

    int mode = jb.mode;
    #pragma unroll
    for (int fm = 0; fm < 2; fm++) {
        #pragma unroll
        for (int fn = 0; fn < 4; fn++) {
            int col = bn0 + wn + fn*16 + fr;
            float bv = jb.bias[col];
            f32x4 vacc = acc[fm][fn];
            #pragma unroll
            for (int r = 0; r < 4; r++) {
                int m = bm0 + wm + fm*16 + fq*4 + r;
                float val = vacc[r] + bv;
                if (mode == 0) {
                    reinterpret_cast<float*>(jb.C)[(long long)m*1024 + col] = val;
                } else if (mode == 1) {
                    reinterpret_cast<unsigned short*>(jb.C)[(long long)m*1024 + col] = f2bf(val);
                } else if (mode == 2) {
                    reinterpret_cast<unsigned short*>(jb.C)[(long long)m*1024 + col] = f2bf(val * 0.125f);
                } else {
                    int bb = m >> 9, ss = m & 511;
                    int hh = col >> 6, dd = col & 63;
                    reinterpret_cast<unsigned short*>(jb.C)[(((long long)bb*16 + hh)*64 + dd)*512 + ss] = f2bf(val);
                }
            }
        }
    }
}

// ---------------------------------------------------------------- rel bias v6 (MFMA)
// biasT[b][h][q][k] = log(max(dot(rel[b,q,k,:], Wr[h,:]) + br[h], 1e-6)) bf16.
// A = rel rows [16 per tile, K=64] (split hi/lo bf16), B = Wr [16 h, K=64]
// (split hi/lo). dot = ahi*whi + alo*whi + ahi*wlo (f32-level accuracy).
// Zero LDS. Block: 4 waves x 4 tiles x 16 rows = 256 rows.
__global__ __launch_bounds__(256) void rel_kernel(
    const float* __restrict__ rel, const float* __restrict__ Wr, const float* __restrict__ br,
    unsigned short* __restrict__ biasT)
{
    int tid = threadIdx.x;
    int wid = tid >> 6, lane = tid & 63;
    int fr = lane & 15, fq = lane >> 4;

    // Wr B-fragments: lane = col h=fr, k = fq*8 + j (frag 0) / +32 (frag 1)
    bf16x8 whi[2], wlo[2];
    {
        const float* wp = Wr + fr*64 + fq*8;
        #pragma unroll
        for (int c = 0; c < 2; c++) {
            #pragma unroll
            for (int j = 0; j < 8; j++) {
                float w = wp[c*32 + j];
                unsigned short hi = f2bf(w);
                whi[c][j] = (short)hi;
                wlo[c][j] = (short)f2bf(w - bf2f(hi));
            }
        }
    }
    float brv = br[fr];

    long long row0 = (long long)blockIdx.x * 256 + wid * 64;
    #pragma unroll
    for (int t = 0; t < 4; t++) {
        long long rtile = row0 + t*16;
        const float* rp = rel + (rtile + fr) * 64 + fq*8;
        float4 r01 = *reinterpret_cast<const float4*>(rp);
        float4 r02 = *reinterpret_cast<const float4*>(rp + 4);
        float4 r11 = *reinterpret_cast<const float4*>(rp + 32);
        float4 r12 = *reinterpret_cast<const float4*>(rp + 36);

        float rf[2][8];
        rf[0][0]=r01.x; rf[0][1]=r01.y; rf[0][2]=r01.z; rf[0][3]=r01.w;
        rf[0][4]=r02.x; rf[0][5]=r02.y; rf[0][6]=r02.z; rf[0][7]=r02.w;
        rf[1][0]=r11.x; rf[1][1]=r11.y; rf[1][2]=r11.z; rf[1][3]=r11.w;
        rf[1][4]=r12.x; rf[1][5]=r12.y; rf[1][6]=r12.z; rf[1][7]=r12.w;

        bf16x8 ahi[2], alo[2];
        #pragma unroll
        for (int c = 0; c < 2; c++) {
            #pragma unroll
            for (int j = 0; j < 8; j++) {
                float x = rf[c][j];
                unsigned short hi = f2bf(x);
                ahi[c][j] = (short)hi;
                alo[c][j] = (short)f2bf(x - bf2f(hi));
            }
        }

        f32x4 acc = {0.f, 0.f, 0.f, 0.f};
        acc = __builtin_amdgcn_mfma_f32_16x16x32_bf16(ahi[0], whi[0], acc, 0, 0, 0);
        acc = __builtin_amdgcn_mfma_f32_16x16x32_bf16(ahi[1], whi[1], acc, 0, 0, 0);
        acc = __builtin_amdgcn_mfma_f32_16x16x32_bf16(alo[0], whi[0], acc, 0, 0, 0);
        acc = __builtin_amdgcn_mfma_f32_16x16x32_bf16(alo[1], whi[1], acc, 0, 0, 0);
        acc = __builtin_amdgcn_mfma_f32_16x16x32_bf16(ahi[0], wlo[0], acc, 0, 0, 0);
        acc = __builtin_amdgcn_mfma_f32_16x16x32_bf16(ahi[1], wlo[1], acc, 0, 0, 0);

        // C-frag: col h = fr, row (=k within tile) = fq*4 + j
        int b  = (int)(rtile >> 18);
        int q  = (int)((rtile >> 9) & 511);
        int k0 = (int)(rtile & 511);
        ushort4 u4;
        unsigned short* up = reinterpret_cast<unsigned short*>(&u4);
        #pragma unroll
        for (int j = 0; j < 4; j++) {
            float val = acc[j] + brv;
            up[j] = f2bf(__logf(fmaxf(val, 1e-6f)));
        }
        *reinterpret_cast<ushort4*>(
            biasT + (((long long)(b*16 + fr)*512 + q) << 9) + k0 + fq*4) = u4;
    }
}

// ---------------------------------------------------------------- attention
__global__ __launch_bounds__(256) void attn_kernel(
    const unsigned short* __restrict__ qh, const unsigned short* __restrict__ kh,
    const unsigned short* __restrict__ vht, const unsigned short* __restrict__ biasT,
    const unsigned char* __restrict__ mask, unsigned short* __restrict__ atted)
{
    __shared__ alignas(16) unsigned short Pl[16][520];
    __shared__ float pmax[4][16];
    __shared__ float psum[4][16];
    int tid = threadIdx.x;
    int wid = tid >> 6, lane = tid & 63;
    int fr = lane & 15, fq = lane >> 4;
    int q0 = blockIdx.x * 16;
    int h = blockIdx.y, b = blockIdx.z;

    bf16x8 aq[2];
    #pragma unroll
    for (int df = 0; df < 2; df++)
        aq[df] = *reinterpret_cast<const bf16x8*>(
            qh + (long long)(b*512 + q0 + fr)*1024 + h*64 + df*32 + fq*8);

    f32x4 s[8];
    #pragma unroll
    for (int kt = 0; kt < 8; kt++) {
        int cb = wid*128 + kt*16;
        f32x4 a4 = {0.f,0.f,0.f,0.f};
        #pragma unroll
        for (int df = 0; df < 2; df++) {
            bf16x8 bk = *reinterpret_cast<const bf16x8*>(
                kh + (long long)(b*512 + cb + fr)*1024 + h*64 + df*32 + fq*8);
            a4 = __builtin_amdgcn_mfma_f32_16x16x32_bf16(aq[df], bk, a4, 0, 0, 0);
        }
        s[kt] = a4;
    }

    const unsigned short* bbase = biasT + ((long long)(b*16 + h)*512 + q0)*512;
    #pragma unroll
    for (int kt = 0; kt < 8; kt++) {
        int col = wid*128 + kt*16 + fr;
        bool mk = mask[b*512 + col] != 0;
        #pragma unroll
        for (int r = 0; r < 4; r++) {
            float bias = bf2f(bbase[(fq*4 + r)*512 + col]);
            float val = s[kt][r] + bias;
            s[kt][r] = mk ? -1e9f : val;
        }
    }

    float rm[4];
    #pragma unroll
    for (int r = 0; r < 4; r++) {
        float m = s[0][r];
        #pragma unroll
        for (int kt = 1; kt < 8; kt++) m = fmaxf(m, s[kt][r]);
        #pragma unroll
        for (int x = 1; x < 16; x <<= 1) m = fmaxf(m, __shfl_xor(m, x, 64));
        rm[r] = m;
    }
    #pragma unroll
    for (int r = 0; r < 4; r++)
        if (fr == r) pmax[wid][fq*4 + r] = rm[r];
    __syncthreads();
    #pragma unroll
    for (int r = 0; r < 4; r++) {
        float m = pmax[0][fq*4 + r];
        m = fmaxf(m, pmax[1][fq*4 + r]);
        m = fmaxf(m, pmax[2][fq*4 + r]);
        m = fmaxf(m, pmax[3][fq*4 + r]);
        rm[r] = m;
    }

    float sum[4] = {0.f, 0.f, 0.f, 0.f};
    #pragma unroll
    for (int kt = 0; kt < 8; kt++) {
        int col = wid*128 + kt*16 + fr;
        #pragma unroll
        for (int r = 0; r < 4; r++) {
            float p = __expf(s[kt][r] - rm[r]);
            sum[r] += p;
            Pl[fq*4 + r][col] = f2bf(p);
        }
    }
    #pragma unroll
    for (int r = 0; r < 4; r++) {
        float sv = sum[r];
        #pragma unroll
        for (int x = 1; x < 16; x <<= 1) sv += __shfl_xor(sv, x, 64);
        sum[r] = sv;
    }
    #pragma unroll
    for (int r = 0; r < 4; r++)
        if (fr == r) psum[wid][fq*4 + r] = sum[r];
    __syncthreads();
    float sumr[4];
    #pragma unroll
    for (int r = 0; r < 4; r++)
        sumr[r] = psum[0][fq*4+r] + psum[1][fq*4+r] + psum[2][fq*4+r] + psum[3][fq*4+r];

    int d0 = wid * 16;
    f32x4 acco = {0.f,0.f,0.f,0.f};
    for (int c = 0; c < 16; c++) {
        bf16x8 pa = *reinterpret_cast<const bf16x8*>(&Pl[fr][c*32 + fq*8]);
        bf16x8 bv = *reinterpret_cast<const bf16x8*>(
            vht + ((long long)(b*16 + h)*64 + d0 + fr)*512 + c*32 + fq*8);
        acco = __builtin_amdgcn_mfma_f32_16x16x32_bf16(pa, bv, acco, 0, 0, 0);
    }
    #pragma unroll
    for (int r = 0; r < 4; r++) {
        float val = acco[r] / sumr[r];
        atted[(long long)(b*512 + q0 + fq*4 + r)*1024 + h*64 + d0 + fr] = f2bf(val);
    }
}

// ---------------------------------------------------------------- launch
extern "C" void kernel_launch(void* const* d_in, const int* in_sizes, int n_in,
                              void* d_out, int out_size, void* d_ws, size_t ws_size,
                              hipStream_t stream)
{
    const float* v    = (const float*)d_in[0];
    const float* k    = (const float*)d_in[1];
    const float* q    = (const float*)d_in[2];
    const unsigned char* mask = (const unsigned char*)d_in[3];
    const float* rel  = (const float*)d_in[4];
    const float* Wv   = (const float*)d_in[5];
    const float* bv   = (const float*)d_in[6];
    const float* Wk   = (const float*)d_in[7];
    const float* bk   = (const float*)d_in[8];
    const float* Wq   = (const float*)d_in[9];
    const float* bq   = (const float*)d_in[10];
    const float* Wr   = (const float*)d_in[11];
    const float* br   = (const float*)d_in[12];
    const float* Wm   = (const float*)d_in[13];
    const float* bm   = (const float*)d_in[14];

    const long long MB = 1 << 20;
    char* W = (char*)d_ws;
    unsigned short* xq    = (unsigned short*)(W + 0*MB);
    unsigned short* xk    = (unsigned short*)(W + 4*MB);
    unsigned short* xv    = (unsigned short*)(W + 8*MB);
    unsigned short* Wqb   = (unsigned short*)(W + 12*MB);
    unsigned short* Wkb   = (unsigned short*)(W + 14*MB);
    unsigned short* Wvb   = (unsigned short*)(W + 16*MB);
    unsigned short* Wmb   = (unsigned short*)(W + 18*MB);
    unsigned short* qhb   = (unsigned short*)(W + 20*MB);
    unsigned short* khb   = (unsigned short*)(W + 24*MB);
    unsigned short* vht   = (unsigned short*)(W + 28*MB);
    unsigned short* atted = (unsigned short*)(W + 32*MB);
    unsigned short* biasT = (unsigned short*)(W + 36*MB);  // 32 MB

    convert_kernel<<<10240, 256, 0, stream>>>(q, k, v, Wq, Wk, Wv, Wm, (unsigned short*)W);

    Gemm3 gp;
    gp.j[0] = { xq, Wqb, bq, (char*)qhb, 2 };
    gp.j[1] = { xk, Wkb, bk, (char*)khb, 1 };
    gp.j[2] = { xv, Wvb, bv, (char*)vht, 3 };
    gemm_bt<<<dim3(32, 8, 3), 256, 0, stream>>>(gp);

    rel_kernel<<<4096, 256, 0, stream>>>(rel, Wr, br, biasT);

    attn_kernel<<<dim3(32, 16, 4), 256, 0, stream>>>(qhb, khb, vht, biasT, mask, atted);

    Gemm3 gf;
    gf.j[0] = { atted, Wmb, bm, (char*)d_out, 0 };
    gf.j[1] = gf.j[0];
    gf.j[2] = gf.j[0];
    gemm_bt<<<dim3(32, 8, 1), 256, 0, stream>>>(gf);
}

// Round 8
// 167.237 us; speedup vs baseline: 1.6019x; 1.0044x over previous
//
#include <hip/hip_runtime.h>
#include <hip/hip_bf16.h>
#include <stdint.h>

// RelMHAtt: B=4 S=512 HIDDEN=1024 H=16 D=64 R=64
// Pipeline: convert(fp32->bf16) -> fused [proj GEMM x3 || rel v6 MFMA] ->
//           attention (register scores) -> out GEMM fp32.
// rel v6: [1M,64]x[64,16] via mfma_f32_16x16x32_bf16, split-precision bf16,
// zero LDS, A-frags straight from global. Fused with proj GEMM (R3 skeleton,
// now with the proven-fast rel role): GEMM blocks [0,768), rel [768,768+4096).

typedef __attribute__((ext_vector_type(8))) short bf16x8;
typedef __attribute__((ext_vector_type(4))) float f32x4;

__device__ inline unsigned short f2bf(float f) {
    __hip_bfloat16 h = __float2bfloat16(f);
    return *reinterpret_cast<unsigned short*>(&h);
}
__device__ inline float bf2f(unsigned short u) {
    unsigned int t = ((unsigned int)u) << 16;
    return __builtin_bit_cast(float, t);
}

// ---------------------------------------------------------------- convert
// dst layout (bf16): xq[2M] xk[2M] xv[2M] Wq[1M] Wk[1M] Wv[1M] Wm[1M]
__global__ __launch_bounds__(256) void convert_kernel(
    const float* __restrict__ q, const float* __restrict__ k, const float* __restrict__ v,
    const float* __restrict__ wq, const float* __restrict__ wk, const float* __restrict__ wv,
    const float* __restrict__ wm, unsigned short* __restrict__ dst)
{
    const long long X = 2097152LL, Wn = 1048576LL;
    long long e = 4LL * ((long long)blockIdx.x * 256 + threadIdx.x);
    const float* s;
    long long o = e;
    if      (o < X)          { s = q; }
    else if (o < 2*X)        { s = k;  o -= X; }
    else if (o < 3*X)        { s = v;  o -= 2*X; }
    else if (o < 3*X + Wn)   { s = wq; o -= 3*X; }
    else if (o < 3*X + 2*Wn) { s = wk; o -= 3*X + Wn; }
    else if (o < 3*X + 3*Wn) { s = wv; o -= 3*X + 2*Wn; }
    else                     { s = wm; o -= 3*X + 3*Wn; }
    float4 val = *reinterpret_cast<const float4*>(s + o);
    ushort4 u;
    u.x = f2bf(val.x); u.y = f2bf(val.y); u.z = f2bf(val.z); u.w = f2bf(val.w);
    *reinterpret_cast<ushort4*>(dst + e) = u;
}

// ---------------------------------------------------------------- GEMM defs
// C[m,n] = sum_k A[m,k]*B[n,k] + bias[n];  BM=64, BN=128, BK=32; 4 waves.
// mode 0: f32 [M,1024]; 1: bf16 [M,1024]; 2: bf16*0.125; 3: bf16 vht[b][h][d][s]
struct GemmJob { const unsigned short* A; const unsigned short* B; const float* bias; char* C; int mode; };
struct Gemm3 { GemmJob j[3]; };

// ---------------------------------------------------------------- fused proj GEMM + rel v6
__global__ __launch_bounds__(256) void gemm_rel(
    Gemm3 g, const float* __restrict__ rel, const float* __restrict__ Wr,
    const float* __restrict__ br, unsigned short* __restrict__ biasT)
{
    __shared__ alignas(16) unsigned short As[2][2048];
    __shared__ alignas(16) unsigned short Bs[2][4096];
    int tid = threadIdx.x;
    int wid = tid >> 6, lane = tid & 63;
    int fr = lane & 15, fq = lane >> 4;

    if (blockIdx.x < 768) {
        // ---------------- GEMM role ----------------
        int bid = blockIdx.x;
        GemmJob jb = g.j[bid >> 8];
        const unsigned short* __restrict__ A = jb.A;
        const unsigned short* __restrict__ B = jb.B;
        int bm0 = ((bid >> 3) & 31) * 64, bn0 = (bid & 7) * 128;
        int wm = (wid >> 1) * 32, wn = (wid & 1) * 64;

        f32x4 acc[2][4];
        f32x4 z4 = {0.f, 0.f, 0.f, 0.f};
        for (int i = 0; i < 2; i++) for (int j = 0; j < 4; j++) acc[i][j] = z4;

        auto stage = [&](int buf, int kt) {
            {
                int ci = tid;
                int row = ci >> 2, kc = ci & 3;
                const unsigned short* ga = A + (long long)(bm0 + row) * 1024 + kt * 32 + kc * 8;
                __builtin_amdgcn_global_load_lds((const __attribute__((address_space(1))) void*)ga,
                    (__attribute__((address_space(3))) void*)(&As[buf][ci * 8]), 16, 0, 0);
            }
            #pragma unroll
            for (int i = 0; i < 2; i++) {
                int ci = tid + 256 * i;
                int row = ci >> 2, kc = ci & 3;
                const unsigned short* gb = B + (long long)(bn0 + row) * 1024 + kt * 32 + kc * 8;
                __builtin_amdgcn_global_load_lds((const __attribute__((address_space(1))) void*)gb,
                    (__attribute__((address_space(3))) void*)(&Bs[buf][ci * 8]), 16, 0, 0);
            }
        };
        auto compute = [&](int buf) {
            bf16x8 a[2], b[4];
            #pragma unroll
            for (int fm = 0; fm < 2; fm++)
                a[fm] = *reinterpret_cast<const bf16x8*>(&As[buf][(wm + fm*16 + fr)*32 + fq*8]);
            #pragma unroll
            for (int fn = 0; fn < 4; fn++)
                b[fn] = *reinterpret_cast<const bf16x8*>(&Bs[buf][(wn + fn*16 + fr)*32 + fq*8]);
            #pragma unroll
            for (int fm = 0; fm < 2; fm++)
                #pragma unroll
                for (int fn = 0; fn < 4; fn++)
                    acc[fm][fn] = __builtin_amdgcn_mfma_f32_16x16x32_bf16(a[fm], b[fn], acc[fm][fn], 0, 0, 0);
        };

        stage(0, 0);
        asm volatile("s_waitcnt vmcnt(0)" ::: "memory");
        __syncthreads();
        int cur = 0;
        for (int kt = 0; kt < 31; kt++) {
            stage(cur ^ 1, kt + 1);
            compute(cur);
            asm volatile("s_waitcnt vmcnt(0)" ::: "memory");
            __syncthreads();
            cur ^= 1;
        }
        compute(cur);

        int mode = jb.mode;
        #pragma unroll
        for (int fm = 0; fm < 2; fm++) {
            #pragma unroll
            for (int fn = 0; fn < 4; fn++) {
                int col = bn0 + wn + fn*16 + fr;
                float bv = jb.bias[col];
                f32x4 vacc = acc[fm][fn];
                #pragma unroll
                for (int r = 0; r < 4; r++) {
                    int m = bm0 + wm + fm*16 + fq*4 + r;
                    float val = vacc[r] + bv;
                    if (mode == 0) {
                        reinterpret_cast<float*>(jb.C)[(long long)m*1024 + col] = val;
                    } else if (mode == 1) {
                        reinterpret_cast<unsigned short*>(jb.C)[(long long)m*1024 + col] = f2bf(val);
                    } else if (mode == 2) {
                        reinterpret_cast<unsigned short*>(jb.C)[(long long)m*1024 + col] = f2bf(val * 0.125f);
                    } else {
                        int bb = m >> 9, ss = m & 511;
                        int hh = col >> 6, dd = col & 63;
                        reinterpret_cast<unsigned short*>(jb.C)[(((long long)bb*16 + hh)*64 + dd)*512 + ss] = f2bf(val);
                    }
                }
            }
        }
    } else {
        // ---------------- rel v6 role (MFMA, zero LDS) ----------------
        // Wr B-fragments: lane = col h=fr, k = fq*8 + j (frag 0) / +32 (frag 1)
        bf16x8 whi[2], wlo[2];
        {
            const float* wp = Wr + fr*64 + fq*8;
            #pragma unroll
            for (int c = 0; c < 2; c++) {
                #pragma unroll
                for (int j = 0; j < 8; j++) {
                    float w = wp[c*32 + j];
                    unsigned short hi = f2bf(w);
                    whi[c][j] = (short)hi;
                    wlo[c][j] = (short)f2bf(w - bf2f(hi));
                }
            }
        }
        float brv = br[fr];

        long long row0 = (long long)(blockIdx.x - 768) * 256 + wid * 64;
        #pragma unroll
        for (int t = 0; t < 4; t++) {
            long long rtile = row0 + t*16;
            const float* rp = rel + (rtile + fr) * 64 + fq*8;
            float4 r01 = *reinterpret_cast<const float4*>(rp);
            float4 r02 = *reinterpret_cast<const float4*>(rp + 4);
            float4 r11 = *reinterpret_cast<const float4*>(rp + 32);
            float4 r12 = *reinterpret_cast<const float4*>(rp + 36);

            float rf[2][8];
            rf[0][0]=r01.x; rf[0][1]=r01.y; rf[0][2]=r01.z; rf[0][3]=r01.w;
            rf[0][4]=r02.x; rf[0][5]=r02.y; rf[0][6]=r02.z; rf[0][7]=r02.w;
            rf[1][0]=r11.x; rf[1][1]=r11.y; rf[1][2]=r11.z; rf[1][3]=r11.w;
            rf[1][4]=r12.x; rf[1][5]=r12.y; rf[1][6]=r12.z; rf[1][7]=r12.w;

            bf16x8 ahi[2], alo[2];
            #pragma unroll
            for (int c = 0; c < 2; c++) {
                #pragma unroll
                for (int j = 0; j < 8; j++) {
                    float x = rf[c][j];
                    unsigned short hi = f2bf(x);
                    ahi[c][j] = (short)hi;
                    alo[c][j] = (short)f2bf(x - bf2f(hi));
                }
            }

            f32x4 acc = {0.f, 0.f, 0.f, 0.f};
            acc = __builtin_amdgcn_mfma_f32_16x16x32_bf16(ahi[0], whi[0], acc, 0, 0, 0);
            acc = __builtin_amdgcn_mfma_f32_16x16x32_bf16(ahi[1], whi[1], acc, 0, 0, 0);
            acc = __builtin_amdgcn_mfma_f32_16x16x32_bf16(alo[0], whi[0], acc, 0, 0, 0);
            acc = __builtin_amdgcn_mfma_f32_16x16x32_bf16(alo[1], whi[1], acc, 0, 0, 0);
            acc = __builtin_amdgcn_mfma_f32_16x16x32_bf16(ahi[0], wlo[0], acc, 0, 0, 0);
            acc = __builtin_amdgcn_mfma_f32_16x16x32_bf16(ahi[1], wlo[1], acc, 0, 0, 0);

            // C-frag: col h = fr, row (=k within tile) = fq*4 + j
            int b  = (int)(rtile >> 18);
            int q  = (int)((rtile >> 9) & 511);
            int k0 = (int)(rtile & 511);
            ushort4 u4;
            unsigned short* up = reinterpret_cast<unsigned short*>(&u4);
            #pragma unroll
            for (int j = 0; j < 4; j++) {
                float val = acc[j] + brv;
                up[j] = f2bf(__logf(fmaxf(val, 1e-6f)));
            }
            *reinterpret_cast<ushort4*>(
                biasT + (((long long)(b*16 + fr)*512 + q) << 9) + k0 + fq*4) = u4;
        }
    }
}

// ---------------------------------------------------------------- final GEMM
__global__ __launch_bounds__(256) void gemm_bt(Gemm3 g)
{
    GemmJob jb = g.j[blockIdx.z];
    const unsigned short* __restrict__ A = jb.A;
    const unsigned short* __restrict__ B = jb.B;
    __shared__ alignas(16) unsigned short As[2][2048];
    __shared__ alignas(16) unsigned short Bs[2][4096];
    int tid = threadIdx.x;
    int bm0 = blockIdx.x * 64, bn0 = blockIdx.y * 128;
    int wid = tid >> 6, lane = tid & 63;
    int fr = lane & 15, fq = lane >> 4;
    int wm = (wid >> 1) * 32, wn = (wid & 1) * 64;

    f32x4 acc[2][4];
    f32x4 z4 = {0.f, 0.f, 0.f, 0.f};
    for (int i = 0; i < 2; i++) for (int j = 0; j < 4; j++) acc[i][j] = z4;

    auto stage = [&](int buf, int kt) {
        {
            int ci = tid;
            int row = ci >> 2, kc = ci & 3;
            const unsigned short* ga = A + (long long)(bm0 + row) * 1024 + kt * 32 + kc * 8;
            __builtin_amdgcn_global_load_lds((const __attribute__((address_space(1))) void*)ga,
                (__attribute__((address_space(3))) void*)(&As[buf][ci * 8]), 16, 0, 0);
        }
        #pragma unroll
        for (int i = 0; i < 2; i++) {
            int ci = tid + 256 * i;
            int row = ci >> 2, kc = ci & 3;
            const unsigned short* gb = B + (long long)(bn0 + row) * 1024 + kt * 32 + kc * 8;
            __builtin_amdgcn_global_load_lds((const __attribute__((address_space(1))) void*)gb,
                (__attribute__((address_space(3))) void*)(&Bs[buf][ci * 8]), 16, 0, 0);
        }
    };
    auto compute = [&](int buf) {
        bf16x8 a[2], b[4];
        #pragma unroll
        for (int fm = 0; fm < 2; fm++)
            a[fm] = *reinterpret_cast<const bf16x8*>(&As[buf][(wm + fm*16 + fr)*32 + fq*8]);
        #pragma unroll
        for (int fn = 0; fn < 4; fn++)
            b[fn] = *reinterpret_cast<const bf16x8*>(&Bs[buf][(wn + fn*16 + fr)*32 + fq*8]);
        #pragma unroll
        for (int fm = 0; fm < 2; fm++)
            #pragma unroll
            for (int fn = 0; fn < 4; fn++)
                acc[fm][fn] = __builtin_amdgcn_mfma_f32_16x16x32_bf16(a[fm], b[fn], acc[fm][fn], 0, 0, 0);
    };

    stage(0, 0);
    asm volatile("s_waitcnt vmcnt(0)" ::: "memory");
    __syncthreads();
    int cur = 0;
    for (int kt = 0; kt < 31; kt++) {
        stage(cur ^ 1, kt + 1);
        compute(cur);
        asm volatile("s_waitcnt vmcnt(0)" ::: "memory");
        __syncthreads();
        cur ^= 1;
    }
    compute(cur);

    int mode = jb.mode;
    #pragma unroll
    for (int fm = 0; fm < 2; fm++) {
        #pragma unroll
        for (int fn = 0; fn < 4; fn++) {
            int col = bn0 + wn + fn*16 + fr;
            float bv = jb.bias[col];
            f32x4 vacc = acc[fm][fn];
            #pragma unroll
            for (int r = 0; r < 4; r++) {
                int m = bm0 + wm + fm*16 + fq*4 + r;
                float val = vacc[r] + bv;
                if (mode == 0) {
                    reinterpret_cast<float*>(jb.C)[(long long)m*1024 + col] = val;
                } else if (mode == 1) {
                    reinterpret_cast<unsigned short*>(jb.C)[(long long)m*1024 + col] = f2bf(val);
                } else if (mode == 2) {
                    reinterpret_cast<unsigned short*>(jb.C)[(long long)m*1024 + col] = f2bf(val * 0.125f);
                } else {
                    int bb = m >> 9, ss = m & 511;
                    int hh = col >> 6, dd = col & 63;
                    reinterpret_cast<unsigned short*>(jb.C)[(((long long)bb*16 + hh)*64 + dd)*512 + ss] = f2bf(val);
                }
            }
        }
    }
}

// ---------------------------------------------------------------- attention
__global__ __launch_bounds__(256) void attn_kernel(
    const unsigned short* __restrict__ qh, const unsigned short* __restrict__ kh,
    const unsigned short* __restrict__ vht, const unsigned short* __restrict__ biasT,
    const unsigned char* __restrict__ mask, unsigned short* __restrict__ atted)
{
    __shared__ alignas(16) unsigned short Pl[16][520];
    __shared__ float pmax[4][16];
    __shared__ float psum[4][16];
    int tid = threadIdx.x;
    int wid = tid >> 6, lane = tid & 63;
    int fr = lane & 15, fq = lane >> 4;
    int q0 = blockIdx.x * 16;
    int h = blockIdx.y, b = blockIdx.z;

    bf16x8 aq[2];
    #pragma unroll
    for (int df = 0; df < 2; df++)
        aq[df] = *reinterpret_cast<const bf16x8*>(
            qh + (long long)(b*512 + q0 + fr)*1024 + h*64 + df*32 + fq*8);

    f32x4 s[8];
    #pragma unroll
    for (int kt = 0; kt < 8; kt++) {
        int cb = wid*128 + kt*16;
        f32x4 a4 = {0.f,0.f,0.f,0.f};
        #pragma unroll
        for (int df = 0; df < 2; df++) {
            bf16x8 bk = *reinterpret_cast<const bf16x8*>(
                kh + (long long)(b*512 + cb + fr)*1024 + h*64 + df*32 + fq*8);
            a4 = __builtin_amdgcn_mfma_f32_16x16x32_bf16(aq[df], bk, a4, 0, 0, 0);
        }
        s[kt] = a4;
    }

    const unsigned short* bbase = biasT + ((long long)(b*16 + h)*512 + q0)*512;
    #pragma unroll
    for (int kt = 0; kt < 8; kt++) {
        int col = wid*128 + kt*16 + fr;
        bool mk = mask[b*512 + col] != 0;
        #pragma unroll
        for (int r = 0; r < 4; r++) {
            float bias = bf2f(bbase[(fq*4 + r)*512 + col]);
            float val = s[kt][r] + bias;
            s[kt][r] = mk ? -1e9f : val;
        }
    }

    float rm[4];
    #pragma unroll
    for (int r = 0; r < 4; r++) {
        float m = s[0][r];
        #pragma unroll
        for (int kt = 1; kt < 8; kt++) m = fmaxf(m, s[kt][r]);
        #pragma unroll
        for (int x = 1; x < 16; x <<= 1) m = fmaxf(m, __shfl_xor(m, x, 64));
        rm[r] = m;
    }
    #pragma unroll
    for (int r = 0; r < 4; r++)
        if (fr == r) pmax[wid][fq*4 + r] = rm[r];
    __syncthreads();
    #pragma unroll
    for (int r = 0; r < 4; r++) {
        float m = pmax[0][fq*4 + r];
        m = fmaxf(m, pmax[1][fq*4 + r]);
        m = fmaxf(m, pmax[2][fq*4 + r]);
        m = fmaxf(m, pmax[3][fq*4 + r]);
        rm[r] = m;
    }

    float sum[4] = {0.f, 0.f, 0.f, 0.f};
    #pragma unroll
    for (int kt = 0; kt < 8; kt++) {
        int col = wid*128 + kt*16 + fr;
        #pragma unroll
        for (int r = 0; r < 4; r++) {
            float p = __expf(s[kt][r] - rm[r]);
            sum[r] += p;
            Pl[fq*4 + r][col] = f2bf(p);
        }
    }
    #pragma unroll
    for (int r = 0; r < 4; r++) {
        float sv = sum[r];
        #pragma unroll
        for (int x = 1; x < 16; x <<= 1) sv += __shfl_xor(sv, x, 64);
        sum[r] = sv;
    }
    #pragma unroll
    for (int r = 0; r < 4; r++)
        if (fr == r) psum[wid][fq*4 + r] = sum[r];
    __syncthreads();
    float sumr[4];
    #pragma unroll
    for (int r = 0; r < 4; r++)
        sumr[r] = psum[0][fq*4+r] + psum[1][fq*4+r] + psum[2][fq*4+r] + psum[3][fq*4+r];

    int d0 = wid * 16;
    f32x4 acco = {0.f,0.f,0.f,0.f};
    for (int c = 0; c < 16; c++) {
        bf16x8 pa = *reinterpret_cast<const bf16x8*>(&Pl[fr][c*32 + fq*8]);
        bf16x8 bv = *reinterpret_cast<const bf16x8*>(
            vht + ((long long)(b*16 + h)*64 + d0 + fr)*512 + c*32 + fq*8);
        acco = __builtin_amdgcn_mfma_f32_16x16x32_bf16(pa, bv, acco, 0, 0, 0);
    }
    #pragma unroll
    for (int r = 0; r < 4; r++) {
        float val = acco[r] / sumr[r];
        atted[(long long)(b*512 + q0 + fq*4 + r)*1024 + h*64 + d0 + fr] = f2bf(val);
    }
}

// ---------------------------------------------------------------- launch
extern "C" void kernel_launch(void* const* d_in, const int* in_sizes, int n_in,
                              void* d_out, int out_size, void* d_ws, size_t ws_size,
                              hipStream_t stream)
{
    const float* v    = (const float*)d_in[0];
    const float* k    = (const float*)d_in[1];
    const float* q    = (const float*)d_in[2];
    const unsigned char* mask = (const unsigned char*)d_in[3];
    const float* rel  = (const float*)d_in[4];
    const float* Wv   = (const float*)d_in[5];
    const float* bv   = (const float*)d_in[6];
    const float* Wk   = (const float*)d_in[7];
    const float* bk   = (const float*)d_in[8];
    const float* Wq   = (const float*)d_in[9];
    const float* bq   = (const float*)d_in[10];
    const float* Wr   = (const float*)d_in[11];
    const float* br   = (const float*)d_in[12];
    const float* Wm   = (const float*)d_in[13];
    const float* bm   = (const float*)d_in[14];

    const long long MB = 1 << 20;
    char* W = (char*)d_ws;
    unsigned short* xq    = (unsigned short*)(W + 0*MB);
    unsigned short* xk    = (unsigned short*)(W + 4*MB);
    unsigned short* xv    = (unsigned short*)(W + 8*MB);
    unsigned short* Wqb   = (unsigned short*)(W + 12*MB);
    unsigned short* Wkb   = (unsigned short*)(W + 14*MB);
    unsigned short* Wvb   = (unsigned short*)(W + 16*MB);
    unsigned short* Wmb   = (unsigned short*)(W + 18*MB);
    unsigned short* qhb   = (unsigned short*)(W + 20*MB);
    unsigned short* khb   = (unsigned short*)(W + 24*MB);
    unsigned short* vht   = (unsigned short*)(W + 28*MB);
    unsigned short* atted = (unsigned short*)(W + 32*MB);
    unsigned short* biasT = (unsigned short*)(W + 36*MB);  // 32 MB

    convert_kernel<<<10240, 256, 0, stream>>>(q, k, v, Wq, Wk, Wv, Wm, (unsigned short*)W);

    Gemm3 gp;
    gp.j[0] = { xq, Wqb, bq, (char*)qhb, 2 };
    gp.j[1] = { xk, Wkb, bk, (char*)khb, 1 };
    gp.j[2] = { xv, Wvb, bv, (char*)vht, 3 };
    gemm_rel<<<768 + 4096, 256, 0, stream>>>(gp, rel, Wr, br, biasT);

    attn_kernel<<<dim3(32, 16, 4), 256, 0, stream>>>(qhb, khb, vht, biasT, mask, atted);

    Gemm3 gf;
    gf.j[0] = { atted, Wmb, bm, (char*)d_out, 0 };
    gf.j[1] = gf.j[0];
    gf.j[2] = gf.j[0];
    gemm_bt<<<dim3(32, 8, 1), 256, 0, stream>>>(gf);
}